// Round 1
// baseline (1424.611 us; speedup 1.0000x reference)
//
#include <hip/hip_runtime.h>
#include <math.h>

#define H 128
#define EPS_BN 1e-5f

// ---------------- CSR build ----------------

__global__ void k_count(const int* __restrict__ col, int E, int* __restrict__ cnt){
  int i = blockIdx.x*blockDim.x + threadIdx.x;
  if (i < E) atomicAdd(&cnt[col[i]], 1);
}

__global__ void k_dinv(const int* __restrict__ cnt, float* __restrict__ dinv, int n){
  int i = blockIdx.x*blockDim.x + threadIdx.x;
  if (i < n) dinv[i] = rsqrtf((float)cnt[i] + 1.0f);   // +1 for self-loop
}

__global__ void k_scan1(const int* __restrict__ cnt, int* __restrict__ off,
                        int* __restrict__ bsum, int n){
  __shared__ int s[1024];
  int t = threadIdx.x;
  int i = blockIdx.x*1024 + t;
  int v = (i < n) ? cnt[i] : 0;
  s[t] = v; __syncthreads();
  for (int d = 1; d < 1024; d <<= 1){
    int x = (t >= d) ? s[t-d] : 0;
    __syncthreads();
    s[t] += x;
    __syncthreads();
  }
  if (i < n) off[i] = s[t] - v;          // block-local exclusive
  if (t == 1023) bsum[blockIdx.x] = s[1023];
}

__global__ void k_scan2(int* bsum, int nb){
  if (threadIdx.x == 0 && blockIdx.x == 0){
    int run = 0;
    for (int b = 0; b < nb; ++b){ int v = bsum[b]; bsum[b] = run; run += v; }
  }
}

__global__ void k_scan3(int* __restrict__ off, int* __restrict__ cursor,
                        const int* __restrict__ bsum, int n, int Etot){
  int i = blockIdx.x*blockDim.x + threadIdx.x;
  if (i < n){ int o = off[i] + bsum[i >> 10]; off[i] = o; cursor[i] = o; }
  if (i == 0) off[n] = Etot;
}

__global__ void k_fill(const int* __restrict__ row, const int* __restrict__ col, int E,
                       const float* __restrict__ dinv, int* __restrict__ cursor,
                       int* __restrict__ esrc, float* __restrict__ ew){
  int i = blockIdx.x*blockDim.x + threadIdx.x;
  if (i < E){
    int c = col[i], r = row[i];
    int p = atomicAdd(&cursor[c], 1);
    esrc[p] = r;
    ew[p]   = dinv[r]*dinv[c];
  }
}

// ---------------- W' = (1-beta) I + beta W ----------------

__global__ void k_wprime(const float* __restrict__ conv_w, float* __restrict__ Wp,
                         float b0, float b1, float b2, float b3){
  int i = blockIdx.x*blockDim.x + threadIdx.x;
  if (i >= 4*H*H) return;
  int l  = i >> 14;
  int rc = i & (H*H - 1);
  int r = rc >> 7, cc = rc & 127;
  float beta = (l==0) ? b0 : (l==1) ? b1 : (l==2) ? b2 : b3;
  float v = beta * conv_w[i];
  if (r == cc) v += (1.0f - beta);
  Wp[i] = v;
}

// ---------------- propagation: one wave per node ----------------
// mode 0: out1 = agg + bias; out2 = same (x0 copy)
// mode 1: out1 = 0.9*agg + 0.1*x0
__global__ void k_prop(const float* __restrict__ h, const int* __restrict__ off,
                       const int* __restrict__ esrc, const float* __restrict__ ew,
                       const float* __restrict__ dinv,
                       float* __restrict__ out1, float* __restrict__ out2,
                       const float* __restrict__ x0, const float* __restrict__ bias,
                       int n, int mode){
  int g = blockIdx.x*blockDim.x + threadIdx.x;
  int node = g >> 6;
  int lane = g & 63;
  if (node >= n) return;
  int e0 = off[node], e1 = off[node+1];
  int idx2 = lane*2;
  float ax = 0.f, ay = 0.f;
  int e = e0;
  for (; e + 1 < e1; e += 2){
    int r0 = esrc[e], r1 = esrc[e+1];
    float w0 = ew[e], w1 = ew[e+1];
    float2 v0 = *(const float2*)(h + (size_t)r0*H + idx2);
    float2 v1 = *(const float2*)(h + (size_t)r1*H + idx2);
    ax += w0*v0.x + w1*v1.x;
    ay += w0*v0.y + w1*v1.y;
  }
  if (e < e1){
    int r0 = esrc[e]; float w0 = ew[e];
    float2 v0 = *(const float2*)(h + (size_t)r0*H + idx2);
    ax += w0*v0.x; ay += w0*v0.y;
  }
  // self-loop term: norm = dinv[c]^2
  float wc = dinv[node]; wc = wc*wc;
  float2 vs = *(const float2*)(h + (size_t)node*H + idx2);
  ax += wc*vs.x; ay += wc*vs.y;

  size_t o = (size_t)node*H + idx2;
  if (mode == 0){
    float zx = ax + bias[idx2];
    float zy = ay + bias[idx2+1];
    out1[o] = zx; out1[o+1] = zy;
    out2[o] = zx; out2[o+1] = zy;
  } else {
    float sx = 0.9f*ax + 0.1f*x0[o];
    float sy = 0.9f*ay + 0.1f*x0[o+1];
    out1[o] = sx; out1[o+1] = sy;
  }
}

// ---------------- fp32 GEMM: C[n x 128] = A[n x K] @ B[K x 128] ----------------
__global__ __launch_bounds__(256) void k_gemm(const float* __restrict__ A,
                                              const float* __restrict__ B,
                                              float* __restrict__ C, int n, int K){
  __shared__ float As[64*36];     // pad stride 36 (16B-aligned rows)
  __shared__ float Bs[32*128];
  int t = threadIdx.x;
  int br = blockIdx.x*64;
  int tx = t & 31;   // cols tx*4 .. +4
  int ty = t >> 5;   // rows ty*8 .. +8
  float acc[8][4];
  #pragma unroll
  for (int j = 0; j < 8; ++j)
    #pragma unroll
    for (int jc = 0; jc < 4; ++jc) acc[j][jc] = 0.f;

  for (int k0 = 0; k0 < K; k0 += 32){
    #pragma unroll
    for (int i = 0; i < 2; ++i){            // A tile 64x32 = 512 float4
      int q = t + i*256;
      int row = q >> 3;
      int kk = (q & 7) * 4;
      int grow = br + row;
      float4 v = make_float4(0.f,0.f,0.f,0.f);
      if (grow < n) v = *(const float4*)(A + (size_t)grow*K + k0 + kk);
      *(float4*)(&As[row*36 + kk]) = v;
    }
    #pragma unroll
    for (int i = 0; i < 4; ++i){            // B tile 32x128 = 1024 float4
      int q = t + i*256;
      int row = q >> 5;
      int cc = (q & 31) * 4;
      float4 v = *(const float4*)(B + (size_t)(k0+row)*H + cc);
      *(float4*)(&Bs[row*128 + cc]) = v;
    }
    __syncthreads();
    #pragma unroll
    for (int kk = 0; kk < 32; ++kk){
      float a[8];
      #pragma unroll
      for (int j = 0; j < 8; ++j) a[j] = As[(ty*8+j)*36 + kk];
      float4 b4 = *(const float4*)(&Bs[kk*128 + tx*4]);
      float b[4] = {b4.x, b4.y, b4.z, b4.w};
      #pragma unroll
      for (int j = 0; j < 8; ++j)
        #pragma unroll
        for (int jc = 0; jc < 4; ++jc)
          acc[j][jc] = fmaf(a[j], b[jc], acc[j][jc]);
    }
    __syncthreads();
  }
  #pragma unroll
  for (int j = 0; j < 8; ++j){
    int grow = br + ty*8 + j;
    if (grow < n){
      float4 v = make_float4(acc[j][0], acc[j][1], acc[j][2], acc[j][3]);
      *(float4*)(C + (size_t)grow*H + tx*4) = v;
    }
  }
}

// ---------------- BatchNorm ----------------

__global__ void k_bnstats(const float* __restrict__ z, float* __restrict__ stats, int n){
  int f = threadIdx.x;            // 128 threads
  int r0 = blockIdx.x*256;
  int r1 = min(r0 + 256, n);
  float s = 0.f, s2 = 0.f;
  for (int r = r0; r < r1; ++r){
    float v = z[(size_t)r*H + f];
    s += v; s2 += v*v;
  }
  atomicAdd(&stats[f], s);
  atomicAdd(&stats[H+f], s2);
}

__global__ void k_bnapply(float* __restrict__ z, const float* __restrict__ stats,
                          const float* __restrict__ gamma, const float* __restrict__ beta,
                          int n){
  int i = blockIdx.x*blockDim.x + threadIdx.x;
  int total = n*H;
  if (i >= total) return;
  int f = i & 127;
  float inv_n = 1.0f/(float)n;
  float mu  = stats[f]*inv_n;
  float var = stats[H+f]*inv_n - mu*mu;
  float sc  = rsqrtf(var + EPS_BN) * gamma[f];
  float v = (z[i] - mu)*sc + beta[f];
  z[i] = v > 0.f ? v : 0.f;
}

// ---------------- launch ----------------

extern "C" void kernel_launch(void* const* d_in, const int* in_sizes, int n_in,
                              void* d_out, int out_size, void* d_ws, size_t ws_size,
                              hipStream_t stream){
  const float* x        = (const float*)d_in[0];
  const int*   ei       = (const int*)  d_in[1];
  const float* lin0_w   = (const float*)d_in[2];
  const float* lin0_b   = (const float*)d_in[3];
  const float* conv_w   = (const float*)d_in[4];
  const float* bn_gamma = (const float*)d_in[5];
  const float* bn_beta  = (const float*)d_in[6];
  float* out = (float*)d_out;

  int N = in_sizes[0] / 256;
  int E = in_sizes[1] / 2;
  const int* row = ei;
  const int* col = ei + E;

  char* ws = (char*)d_ws;
  size_t p = 0;
  auto alloc = [&](size_t bytes)->char*{
    char* r = ws + p; p = (p + bytes + 255) & ~(size_t)255; return r;
  };
  int*   cnt    = (int*)  alloc((size_t)N*4);
  int*   off    = (int*)  alloc((size_t)(N+1)*4);
  int*   cursor = (int*)  alloc((size_t)N*4);
  float* dinv   = (float*)alloc((size_t)N*4);
  int*   bsum   = (int*)  alloc(512*4);
  int*   esrc   = (int*)  alloc((size_t)E*4);
  float* ewt    = (float*)alloc((size_t)E*4);
  float* A      = (float*)alloc((size_t)N*H*4);   // z
  float* C      = (float*)alloc((size_t)N*H*4);   // xw / h / s
  float* Wp     = (float*)alloc((size_t)4*H*H*4);
  float* stats  = (float*)alloc(2*H*4);
  // x0 lives in d_out until the final GEMM overwrites it

  float betas[4];
  for (int i = 0; i < 4; ++i) betas[i] = logf(0.5f/(float)(i+1) + 1.0f);

  // ---- CSR build ----
  hipMemsetAsync(cnt, 0, (size_t)N*4, stream);
  k_count<<<(E+255)/256, 256, 0, stream>>>(col, E, cnt);
  k_dinv <<<(N+255)/256, 256, 0, stream>>>(cnt, dinv, N);
  int nb = (N + 1023)/1024;
  k_scan1<<<nb, 1024, 0, stream>>>(cnt, off, bsum, N);
  k_scan2<<<1, 64, 0, stream>>>(bsum, nb);
  k_scan3<<<(N+255)/256, 256, 0, stream>>>(off, cursor, bsum, N, E);
  k_fill <<<(E+255)/256, 256, 0, stream>>>(row, col, E, dinv, cursor, esrc, ewt);

  k_wprime<<<(4*H*H+255)/256, 256, 0, stream>>>(conv_w, Wp,
            betas[0], betas[1], betas[2], betas[3]);

  // ---- input layer: xw = x @ lin0_w ; z = prop(xw)+b ; x0 = z ----
  k_gemm<<<(N+63)/64, 256, 0, stream>>>(x, lin0_w, C, N, 256);
  k_prop<<<(N+3)/4, 256, 0, stream>>>(C, off, esrc, ewt, dinv,
                                      A, out, nullptr, lin0_b, N, 0);

  // ---- 4 GCN2Conv layers ----
  for (int l = 0; l < 4; ++l){
    // s = 0.9*prop(z) + 0.1*x0  -> C
    k_prop<<<(N+3)/4, 256, 0, stream>>>(A, off, esrc, ewt, dinv,
                                        C, nullptr, out, nullptr, N, 1);
    float* dst = (l < 3) ? A : out;
    k_gemm<<<(N+63)/64, 256, 0, stream>>>(C, Wp + l*H*H, dst, N, 128);
    if (l < 3){
      hipMemsetAsync(stats, 0, 2*H*4, stream);
      k_bnstats<<<(N+255)/256, 128, 0, stream>>>(A, stats, N);
      k_bnapply<<<(N*H+255)/256, 256, 0, stream>>>(A, stats,
                 bn_gamma + l*H, bn_beta + l*H, N);
    }
  }
}

// Round 2
// 1074.313 us; speedup vs baseline: 1.3261x; 1.3261x over previous
//
#include <hip/hip_runtime.h>
#include <hip/hip_bf16.h>
#include <math.h>

#define H 128
#define EPS_BN 1e-5f

typedef __attribute__((ext_vector_type(8))) short short8;
typedef __attribute__((ext_vector_type(4))) float f32x4;

__device__ __forceinline__ float bf2f(ushort u){
  union { float f; uint v; } x; x.v = ((uint)u) << 16; return x.f;
}
__device__ __forceinline__ ushort f2bf(float f){
  union { float f; uint v; } x; x.f = f;
  uint v = x.v;
  uint r = v + 0x7fff + ((v >> 16) & 1);   // RNE
  return (ushort)(r >> 16);
}

// ---------------- CSR build ----------------

__global__ void k_count(const int* __restrict__ col, int E, int* __restrict__ cnt){
  int i = blockIdx.x*blockDim.x + threadIdx.x;
  if (i < E) atomicAdd(&cnt[col[i]], 1);
}

__global__ void k_dinv(const int* __restrict__ cnt, float* __restrict__ dinv, int n){
  int i = blockIdx.x*blockDim.x + threadIdx.x;
  if (i < n) dinv[i] = rsqrtf((float)cnt[i] + 1.0f);   // +1 self-loop
}

__global__ void k_scan1(const int* __restrict__ cnt, int* __restrict__ off,
                        int* __restrict__ bsum, int n){
  __shared__ int s[1024];
  int t = threadIdx.x;
  int i = blockIdx.x*1024 + t;
  int v = (i < n) ? cnt[i] : 0;
  s[t] = v; __syncthreads();
  for (int d = 1; d < 1024; d <<= 1){
    int x = (t >= d) ? s[t-d] : 0;
    __syncthreads();
    s[t] += x;
    __syncthreads();
  }
  if (i < n) off[i] = s[t] - v;
  if (t == 1023) bsum[blockIdx.x] = s[1023];
}

__global__ void k_scan2(int* bsum, int nb){
  if (threadIdx.x == 0 && blockIdx.x == 0){
    int run = 0;
    for (int b = 0; b < nb; ++b){ int v = bsum[b]; bsum[b] = run; run += v; }
  }
}

__global__ void k_scan3(int* __restrict__ off, int* __restrict__ cursor,
                        const int* __restrict__ bsum, int n, int Etot){
  int i = blockIdx.x*blockDim.x + threadIdx.x;
  if (i < n){ int o = off[i] + bsum[i >> 10]; off[i] = o; cursor[i] = o; }
  if (i == 0) off[n] = Etot;
}

__global__ void k_fill(const int* __restrict__ row, const int* __restrict__ col, int E,
                       const float* __restrict__ dinv, int* __restrict__ cursor,
                       int* __restrict__ esrc, float* __restrict__ ew){
  int i = blockIdx.x*blockDim.x + threadIdx.x;
  if (i < E){
    int c = col[i], r = row[i];
    int p = atomicAdd(&cursor[c], 1);
    esrc[p] = r;
    ew[p]   = dinv[r]*dinv[c];
  }
}

// ---------------- weight prep: bf16, transposed, beta-folded ----------------
// lin0T[n][k] = bf16(lin0_w[k][n])           (128 x 256)
// WpT[l][n][k] = bf16(beta_l*W[l][k][n] + (k==n)(1-beta_l))   (4 x 128 x 128)

__global__ void k_prepw(const float* __restrict__ lin0_w, const float* __restrict__ conv_w,
                        ushort* __restrict__ lin0T, ushort* __restrict__ WpT,
                        float b0, float b1, float b2, float b3){
  int i = blockIdx.x*blockDim.x + threadIdx.x;
  if (i < 128*256){
    int nn = i >> 8, k = i & 255;
    lin0T[i] = f2bf(lin0_w[k*128 + nn]);
  } else if (i < 128*256 + 4*128*128){
    int j = i - 128*256;
    int ll = j >> 14, rc = j & 16383;
    int nn = rc >> 7, k = rc & 127;
    float beta = (ll==0)?b0:(ll==1)?b1:(ll==2)?b2:b3;
    float v = beta * conv_w[ll*16384 + k*128 + nn];
    if (k == nn) v += 1.0f - beta;
    WpT[j] = f2bf(v);
  }
}

// ---------------- propagation (bf16 h): one wave per node ----------------
// half-wave per edge: lanes 0-31 -> edge e, lanes 32-63 -> edge e+1,
// each lane owns 4 feats (uint2 = 4 bf16 = 8B).
// mode 0: z = agg + bias -> out1, out2 (x0 copy)
// mode 1: s = 0.9*agg + 0.1*x0 -> out1

__global__ __launch_bounds__(256) void k_prop(
    const ushort* __restrict__ h, const int* __restrict__ off,
    const int* __restrict__ esrc, const float* __restrict__ ew,
    const float* __restrict__ dinv,
    ushort* __restrict__ out1, ushort* __restrict__ out2,
    const ushort* __restrict__ x0, const float* __restrict__ bias,
    int n, int mode){
  int g = blockIdx.x*blockDim.x + threadIdx.x;
  int node = g >> 6;
  if (node >= n) return;
  int lane = g & 63;
  int half = lane >> 5;
  int hl   = lane & 31;
  int e0 = off[node], e1 = off[node+1];
  float a0=0.f, a1=0.f, a2=0.f, a3=0.f;
  for (int e = e0; e < e1; e += 2){
    int ee = e + half;
    if (ee < e1){
      int r = esrc[ee];
      float w = ew[ee];
      uint2 v = *(const uint2*)(h + (size_t)r*H + hl*4);
      a0 += w * bf2f((ushort)(v.x & 0xffff));
      a1 += w * bf2f((ushort)(v.x >> 16));
      a2 += w * bf2f((ushort)(v.y & 0xffff));
      a3 += w * bf2f((ushort)(v.y >> 16));
    }
  }
  if (half == 0){  // self-loop term, added exactly once
    float wc = dinv[node]; wc *= wc;
    uint2 v = *(const uint2*)(h + (size_t)node*H + hl*4);
    a0 += wc * bf2f((ushort)(v.x & 0xffff));
    a1 += wc * bf2f((ushort)(v.x >> 16));
    a2 += wc * bf2f((ushort)(v.y & 0xffff));
    a3 += wc * bf2f((ushort)(v.y >> 16));
  }
  // combine halves
  a0 += __shfl(a0, lane ^ 32);
  a1 += __shfl(a1, lane ^ 32);
  a2 += __shfl(a2, lane ^ 32);
  a3 += __shfl(a3, lane ^ 32);
  if (half == 0){
    size_t o = (size_t)node*H + hl*4;
    uint2 pk;
    if (mode == 0){
      float4 b = *(const float4*)(bias + hl*4);
      ushort z0 = f2bf(a0 + b.x), z1 = f2bf(a1 + b.y);
      ushort z2 = f2bf(a2 + b.z), z3 = f2bf(a3 + b.w);
      pk.x = (uint)z0 | ((uint)z1 << 16);
      pk.y = (uint)z2 | ((uint)z3 << 16);
      *(uint2*)(out1 + o) = pk;
      *(uint2*)(out2 + o) = pk;
    } else {
      uint2 xv = *(const uint2*)(x0 + o);
      float s0 = 0.9f*a0 + 0.1f*bf2f((ushort)(xv.x & 0xffff));
      float s1 = 0.9f*a1 + 0.1f*bf2f((ushort)(xv.x >> 16));
      float s2 = 0.9f*a2 + 0.1f*bf2f((ushort)(xv.y & 0xffff));
      float s3 = 0.9f*a3 + 0.1f*bf2f((ushort)(xv.y >> 16));
      pk.x = (uint)f2bf(s0) | ((uint)f2bf(s1) << 16);
      pk.y = (uint)f2bf(s2) | ((uint)f2bf(s3) << 16);
      *(uint2*)(out1 + o) = pk;
    }
  }
}

// ---------------- MFMA bf16 GEMM: C[n x 128] = A[n x K] @ BT[128 x K]^T ----
// 64x128 tile, 4 waves (each 16 rows x 128 cols = 8 mfma 16x16x32 tiles)

template<int K, bool AF32, bool OUTF32>
__global__ __launch_bounds__(256) void k_gemm(
    const void* __restrict__ Av, const ushort* __restrict__ BT,
    void* __restrict__ Cv, int n){
  __shared__ ushort As[64*32];
  __shared__ ushort Bs[128*32];
  int t = threadIdx.x;
  int br = blockIdx.x * 64;
  int w = t >> 6, l = t & 63;
  int lr = l & 15, lk = l >> 4;
  int swz = (lr >> 1) & 3;

  f32x4 acc[8];
  #pragma unroll
  for (int i = 0; i < 8; ++i) acc[i] = (f32x4){0.f,0.f,0.f,0.f};

  int sar = t >> 2;                 // A stage row 0..63
  int sab = t & 3;                  // A stage 16B block 0..3
  int sa_off = sar*32 + ((sab ^ ((sar>>1)&3))*8);

  const float*  Af = (const float*)Av;
  const ushort* Ab = (const ushort*)Av;

  for (int k0 = 0; k0 < K; k0 += 32){
    int grow = br + sar;
    if (AF32){
      float4 v0 = make_float4(0.f,0.f,0.f,0.f), v1 = v0;
      if (grow < n){
        v0 = *(const float4*)(Af + (size_t)grow*K + k0 + sab*8);
        v1 = *(const float4*)(Af + (size_t)grow*K + k0 + sab*8 + 4);
      }
      ushort tmp[8] = {f2bf(v0.x),f2bf(v0.y),f2bf(v0.z),f2bf(v0.w),
                       f2bf(v1.x),f2bf(v1.y),f2bf(v1.z),f2bf(v1.w)};
      *(uint4*)(&As[sa_off]) = *(const uint4*)tmp;
    } else {
      uint4 v = make_uint4(0u,0u,0u,0u);
      if (grow < n) v = *(const uint4*)(Ab + (size_t)grow*K + k0 + sab*8);
      *(uint4*)(&As[sa_off]) = v;
    }
    #pragma unroll
    for (int i = 0; i < 2; ++i){   // B tile 128x32
      int q = t + i*256;
      int nrow = q >> 2, bb = q & 3;
      uint4 v = *(const uint4*)(BT + (size_t)nrow*K + k0 + bb*8);
      *(uint4*)(&Bs[nrow*32 + ((bb ^ ((nrow>>1)&3))*8)]) = v;
    }
    __syncthreads();
    short8 af = *(const short8*)(&As[(w*16+lr)*32 + ((lk ^ swz)*8)]);
    #pragma unroll
    for (int tn = 0; tn < 8; ++tn){
      short8 bf = *(const short8*)(&Bs[(tn*16+lr)*32 + ((lk ^ swz)*8)]);
      acc[tn] = __builtin_amdgcn_mfma_f32_16x16x32_bf16(af, bf, acc[tn], 0, 0, 0);
    }
    __syncthreads();
  }
  int orow = br + w*16 + lk*4;      // C/D: col = lr, row = lk*4 + j
  if (OUTF32){
    float* C = (float*)Cv;
    #pragma unroll
    for (int tn = 0; tn < 8; ++tn)
      #pragma unroll
      for (int j = 0; j < 4; ++j)
        if (orow + j < n) C[(size_t)(orow+j)*H + tn*16 + lr] = acc[tn][j];
  } else {
    uint* Cu = (uint*)Cv;
    #pragma unroll
    for (int tn = 0; tn < 8; ++tn){
      #pragma unroll
      for (int j = 0; j < 4; ++j){
        float mine  = acc[tn][j];
        float other = __shfl(mine, l ^ 1);
        if (!(l & 1) && (orow + j) < n){
          uint pk = (uint)f2bf(mine) | ((uint)f2bf(other) << 16);
          Cu[(size_t)(orow+j)*64 + tn*8 + (lr >> 1)] = pk;
        }
      }
    }
  }
}

// ---------------- BatchNorm (bf16 activations) ----------------

__global__ void k_bnstats(const ushort* __restrict__ z, float* __restrict__ stats, int n){
  int f = threadIdx.x;            // 128 threads
  int r0 = blockIdx.x*256;
  int r1 = min(r0 + 256, n);
  float s = 0.f, s2 = 0.f;
  for (int r = r0; r < r1; ++r){
    float v = bf2f(z[(size_t)r*H + f]);
    s += v; s2 += v*v;
  }
  atomicAdd(&stats[f], s);
  atomicAdd(&stats[H+f], s2);
}

__global__ void k_bnapply(ushort* __restrict__ z, const float* __restrict__ stats,
                          const float* __restrict__ gamma, const float* __restrict__ beta,
                          int n, float inv_n){
  int i = blockIdx.x*blockDim.x + threadIdx.x;   // one per 2 elems
  if (i >= n*64) return;
  int fc = (i & 63) * 2;
  uint v = ((uint*)z)[i];
  float mu0 = stats[fc]  * inv_n, mu1 = stats[fc+1]  * inv_n;
  float vr0 = stats[H+fc]* inv_n - mu0*mu0;
  float vr1 = stats[H+fc+1]*inv_n - mu1*mu1;
  float sc0 = rsqrtf(vr0 + EPS_BN) * gamma[fc];
  float sc1 = rsqrtf(vr1 + EPS_BN) * gamma[fc+1];
  float y0 = (bf2f((ushort)(v & 0xffff)) - mu0)*sc0 + beta[fc];
  float y1 = (bf2f((ushort)(v >> 16))   - mu1)*sc1 + beta[fc+1];
  y0 = y0 > 0.f ? y0 : 0.f;
  y1 = y1 > 0.f ? y1 : 0.f;
  ((uint*)z)[i] = (uint)f2bf(y0) | ((uint)f2bf(y1) << 16);
}

// ---------------- launch ----------------

extern "C" void kernel_launch(void* const* d_in, const int* in_sizes, int n_in,
                              void* d_out, int out_size, void* d_ws, size_t ws_size,
                              hipStream_t stream){
  const float* x        = (const float*)d_in[0];
  const int*   ei       = (const int*)  d_in[1];
  const float* lin0_w   = (const float*)d_in[2];
  const float* lin0_b   = (const float*)d_in[3];
  const float* conv_w   = (const float*)d_in[4];
  const float* bn_gamma = (const float*)d_in[5];
  const float* bn_beta  = (const float*)d_in[6];
  float* out = (float*)d_out;

  int N = in_sizes[0] / 256;
  int E = in_sizes[1] / 2;
  const int* row = ei;
  const int* col = ei + E;

  char* ws = (char*)d_ws;
  size_t p = 0;
  auto alloc = [&](size_t bytes)->char*{
    char* r = ws + p; p = (p + bytes + 255) & ~(size_t)255; return r;
  };
  int*    cnt    = (int*)   alloc((size_t)N*4);
  int*    off    = (int*)   alloc((size_t)(N+1)*4);
  int*    cursor = (int*)   alloc((size_t)N*4);
  float*  dinv   = (float*) alloc((size_t)N*4);
  int*    bsum   = (int*)   alloc(512*4);
  int*    esrc   = (int*)   alloc((size_t)E*4);
  float*  ewt    = (float*) alloc((size_t)E*4);
  ushort* zb     = (ushort*)alloc((size_t)N*H*2);   // z (layer activations)
  ushort* sb     = (ushort*)alloc((size_t)N*H*2);   // xw / s
  ushort* x0b    = (ushort*)alloc((size_t)N*H*2);   // x0
  ushort* lin0T  = (ushort*)alloc(128*256*2);
  ushort* WpT    = (ushort*)alloc(4*128*128*2);
  float*  stats  = (float*) alloc(2*H*4);

  float betas[4];
  for (int i = 0; i < 4; ++i) betas[i] = logf(0.5f/(float)(i+1) + 1.0f);

  // ---- CSR build ----
  hipMemsetAsync(cnt, 0, (size_t)N*4, stream);
  k_count<<<(E+255)/256, 256, 0, stream>>>(col, E, cnt);
  k_dinv <<<(N+255)/256, 256, 0, stream>>>(cnt, dinv, N);
  int nb = (N + 1023)/1024;
  k_scan1<<<nb, 1024, 0, stream>>>(cnt, off, bsum, N);
  k_scan2<<<1, 64, 0, stream>>>(bsum, nb);
  k_scan3<<<(N+255)/256, 256, 0, stream>>>(off, cursor, bsum, N, E);
  k_fill <<<(E+255)/256, 256, 0, stream>>>(row, col, E, dinv, cursor, esrc, ewt);

  k_prepw<<<(128*256 + 4*128*128 + 255)/256, 256, 0, stream>>>(
      lin0_w, conv_w, lin0T, WpT, betas[0], betas[1], betas[2], betas[3]);

  int gemm_blocks = (N + 63)/64;
  int prop_blocks = ((N*64) + 255)/256;

  // ---- input layer: xw = x @ lin0 ; z = prop(xw)+b ; x0 = z ----
  k_gemm<256, true, false><<<gemm_blocks, 256, 0, stream>>>(x, lin0T, sb, N);
  k_prop<<<prop_blocks, 256, 0, stream>>>(sb, off, esrc, ewt, dinv,
                                          zb, x0b, nullptr, lin0_b, N, 0);

  // ---- 4 GCN2Conv layers ----
  float inv_n = 1.0f/(float)N;
  for (int l = 0; l < 4; ++l){
    k_prop<<<prop_blocks, 256, 0, stream>>>(zb, off, esrc, ewt, dinv,
                                            sb, nullptr, x0b, nullptr, N, 1);
    if (l < 3){
      k_gemm<128, false, false><<<gemm_blocks, 256, 0, stream>>>(
          sb, WpT + l*128*128, zb, N);
      hipMemsetAsync(stats, 0, 2*H*4, stream);
      k_bnstats<<<(N+255)/256, 128, 0, stream>>>(zb, stats, N);
      k_bnapply<<<((N*64)+255)/256, 256, 0, stream>>>(zb, stats,
                 bn_gamma + l*H, bn_beta + l*H, N, inv_n);
    } else {
      k_gemm<128, false, true><<<gemm_blocks, 256, 0, stream>>>(
          sb, WpT + 3*128*128, out, N);
    }
  }
}

// Round 3
// 897.836 us; speedup vs baseline: 1.5867x; 1.1966x over previous
//
#include <hip/hip_runtime.h>
#include <hip/hip_bf16.h>
#include <math.h>

#define H 128
#define EPS_BN 1e-5f
#define RSTATS 16

typedef __attribute__((ext_vector_type(8))) short short8;
typedef __attribute__((ext_vector_type(4))) float f32x4;

__device__ __forceinline__ float bf2f(ushort u){
  union { float f; uint v; } x; x.v = ((uint)u) << 16; return x.f;
}
__device__ __forceinline__ ushort f2bf(float f){
  union { float f; uint v; } x; x.f = f;
  uint v = x.v;
  uint r = v + 0x7fff + ((v >> 16) & 1);   // RNE
  return (ushort)(r >> 16);
}

__device__ __forceinline__ void acc8(float* a, uint4 v, float wt){
  a[0] += wt*bf2f((ushort)(v.x & 0xffff)); a[1] += wt*bf2f((ushort)(v.x >> 16));
  a[2] += wt*bf2f((ushort)(v.y & 0xffff)); a[3] += wt*bf2f((ushort)(v.y >> 16));
  a[4] += wt*bf2f((ushort)(v.z & 0xffff)); a[5] += wt*bf2f((ushort)(v.z >> 16));
  a[6] += wt*bf2f((ushort)(v.w & 0xffff)); a[7] += wt*bf2f((ushort)(v.w >> 16));
}
__device__ __forceinline__ void acc8bn(float* a, uint4 v, float wt,
                                       const float* sc, const float* sh){
  float z[8] = { bf2f((ushort)(v.x & 0xffff)), bf2f((ushort)(v.x >> 16)),
                 bf2f((ushort)(v.y & 0xffff)), bf2f((ushort)(v.y >> 16)),
                 bf2f((ushort)(v.z & 0xffff)), bf2f((ushort)(v.z >> 16)),
                 bf2f((ushort)(v.w & 0xffff)), bf2f((ushort)(v.w >> 16)) };
  #pragma unroll
  for (int j = 0; j < 8; ++j){
    float y = fmaf(z[j], sc[j], sh[j]);
    y = fmaxf(y, 0.f);
    a[j] += wt*y;
  }
}

// ---------------- CSR build ----------------

__global__ void k_count(const int* __restrict__ col, int E, int* __restrict__ cnt){
  int i = blockIdx.x*blockDim.x + threadIdx.x;
  if (i < E) atomicAdd(&cnt[col[i]], 1);
}

__global__ void k_dinv(const int* __restrict__ cnt, float* __restrict__ dinv, int n){
  int i = blockIdx.x*blockDim.x + threadIdx.x;
  if (i < n) dinv[i] = rsqrtf((float)cnt[i] + 1.0f);   // +1 self-loop
}

__global__ void k_scan1(const int* __restrict__ cnt, int* __restrict__ off,
                        int* __restrict__ bsum, int n){
  __shared__ int s[1024];
  int t = threadIdx.x;
  int i = blockIdx.x*1024 + t;
  int v = (i < n) ? cnt[i] : 0;
  s[t] = v; __syncthreads();
  for (int d = 1; d < 1024; d <<= 1){
    int x = (t >= d) ? s[t-d] : 0;
    __syncthreads();
    s[t] += x;
    __syncthreads();
  }
  if (i < n) off[i] = s[t] - v;
  if (t == 1023) bsum[blockIdx.x] = s[1023];
}

__global__ void k_scan2(int* bsum, int nb){
  int l = threadIdx.x;           // 64 threads, 1 block
  int carry = 0;
  for (int b0 = 0; b0 < nb; b0 += 64){
    int i = b0 + l;
    int orig = (i < nb) ? bsum[i] : 0;
    int v = orig;
    #pragma unroll
    for (int d = 1; d < 64; d <<= 1){
      int x = __shfl_up(v, d);
      if (l >= d) v += x;
    }
    if (i < nb) bsum[i] = carry + v - orig;   // exclusive
    carry += __shfl(v, 63);
  }
}

__global__ void k_scan3(int* __restrict__ off, int* __restrict__ cursor,
                        const int* __restrict__ bsum, int n, int Etot){
  int i = blockIdx.x*blockDim.x + threadIdx.x;
  if (i < n){ int o = off[i] + bsum[i >> 10]; off[i] = o; cursor[i] = o; }
  if (i == 0) off[n] = Etot;
}

__global__ void k_fill(const int* __restrict__ row, const int* __restrict__ col, int E,
                       const float* __restrict__ dinv, int* __restrict__ cursor,
                       uint2* __restrict__ edge){
  int i = blockIdx.x*blockDim.x + threadIdx.x;
  if (i < E){
    int c = col[i], r = row[i];
    int p = atomicAdd(&cursor[c], 1);
    edge[p] = make_uint2((uint)r, __float_as_uint(dinv[r]*dinv[c]));
  }
}

// ---------------- weight prep: bf16, transposed, beta-folded ----------------

__global__ void k_prepw(const float* __restrict__ lin0_w, const float* __restrict__ conv_w,
                        ushort* __restrict__ lin0T, ushort* __restrict__ WpT,
                        float b0, float b1, float b2, float b3){
  int i = blockIdx.x*blockDim.x + threadIdx.x;
  if (i < 128*256){
    int nn = i >> 8, k = i & 255;
    lin0T[i] = f2bf(lin0_w[k*128 + nn]);
  } else if (i < 128*256 + 4*128*128){
    int j = i - 128*256;
    int ll = j >> 14, rc = j & 16383;
    int nn = rc >> 7, k = rc & 127;
    float beta = (ll==0)?b0:(ll==1)?b1:(ll==2)?b2:b3;
    float v = beta * conv_w[ll*16384 + k*128 + nn];
    if (k == nn) v += 1.0f - beta;
    WpT[j] = f2bf(v);
  }
}

// ---------------- input-layer prop: z = agg(xw)+b ; x0 = z ----------------
// quarter-wave per edge: 16 lanes x 16B (8 bf16) per row gather

__global__ __launch_bounds__(256) void k_prop0(
    const ushort* __restrict__ h, const int* __restrict__ off,
    const uint2* __restrict__ edge, const float* __restrict__ dinv,
    const float* __restrict__ bias,
    ushort* __restrict__ z, ushort* __restrict__ x0, int n){
  int g = blockIdx.x*blockDim.x + threadIdx.x;
  int node = g >> 6;
  if (node >= n) return;
  int l = g & 63, lr = l & 15, q = l >> 4;
  int e0 = off[node], e1 = off[node+1];
  float a[8];
  #pragma unroll
  for (int j = 0; j < 8; ++j) a[j] = 0.f;
  for (int e = e0 + q; e < e1; e += 4){
    uint2 ed = edge[e];
    uint4 v = *(const uint4*)(h + (size_t)ed.x*H + lr*8);
    acc8(a, v, __uint_as_float(ed.y));
  }
  if (q == 0){
    float wc = dinv[node]; wc *= wc;
    uint4 v = *(const uint4*)(h + (size_t)node*H + lr*8);
    acc8(a, v, wc);
  }
  #pragma unroll
  for (int j = 0; j < 8; ++j){
    a[j] += __shfl(a[j], l ^ 16);
    a[j] += __shfl(a[j], l ^ 32);
  }
  if (q == 0){
    float4 b0 = *(const float4*)(bias + lr*8);
    float4 b1 = *(const float4*)(bias + lr*8 + 4);
    uint4 pk;
    pk.x = (uint)f2bf(a[0]+b0.x) | ((uint)f2bf(a[1]+b0.y) << 16);
    pk.y = (uint)f2bf(a[2]+b0.z) | ((uint)f2bf(a[3]+b0.w) << 16);
    pk.z = (uint)f2bf(a[4]+b1.x) | ((uint)f2bf(a[5]+b1.y) << 16);
    pk.w = (uint)f2bf(a[6]+b1.z) | ((uint)f2bf(a[7]+b1.w) << 16);
    size_t o = (size_t)node*H + lr*8;
    *(uint4*)(z  + o) = pk;
    *(uint4*)(x0 + o) = pk;
  }
}

// ---------------- fused layer: prop -> LDS s-tile -> MFMA GEMM -> z (+stats) --
// block = 256 thr (4 waves) = 64 nodes. Wave w: nodes [w*16, w*16+16).
// GEMM: wave w owns output cols [w*32, w*32+32); B (W'^T) held in registers.

template<bool BNIN, bool STATS, bool OUTF32>
__global__ __launch_bounds__(256) void k_layer(
    const ushort* __restrict__ zin, const ushort* __restrict__ x0,
    const int* __restrict__ off, const uint2* __restrict__ edge,
    const float* __restrict__ dinv, const ushort* __restrict__ BT,
    const float* __restrict__ scsh,
    void* __restrict__ zout, float* __restrict__ stats, int n)
{
  __shared__ ushort Sm[64*128];   // swizzled s tile: row*128 + (blk16^(row&15))*8
  int t = threadIdx.x;
  int w = t >> 6, l = t & 63;
  int lr = l & 15, q = l >> 4;
  int base = blockIdx.x * 64;

  float sc[8], sh[8];
  if (BNIN){
    #pragma unroll
    for (int j = 0; j < 8; ++j){
      sc[j] = scsh[lr*8 + j];
      sh[j] = scsh[128 + lr*8 + j];
    }
  }

  // ---- prop phase ----
  for (int nd = 0; nd < 16; ++nd){
    int node = base + w*16 + nd;
    float a[8];
    #pragma unroll
    for (int j = 0; j < 8; ++j) a[j] = 0.f;
    if (node < n){
      int e0 = off[node], e1 = off[node+1];
      for (int e = e0 + q; e < e1; e += 4){
        uint2 ed = edge[e];
        uint4 v = *(const uint4*)(zin + (size_t)ed.x*H + lr*8);
        float wt = __uint_as_float(ed.y);
        if (BNIN) acc8bn(a, v, wt, sc, sh); else acc8(a, v, wt);
      }
      if (q == 0){
        float wc = dinv[node]; wc *= wc;
        uint4 v = *(const uint4*)(zin + (size_t)node*H + lr*8);
        if (BNIN) acc8bn(a, v, wc, sc, sh); else acc8(a, v, wc);
      }
    }
    #pragma unroll
    for (int j = 0; j < 8; ++j){
      a[j] += __shfl(a[j], l ^ 16);
      a[j] += __shfl(a[j], l ^ 32);
    }
    if (q == 0){
      int row = w*16 + nd;
      uint4 pk = make_uint4(0u,0u,0u,0u);
      if (node < n){
        uint4 xv = *(const uint4*)(x0 + (size_t)node*H + lr*8);
        float s0 = 0.9f*a[0] + 0.1f*bf2f((ushort)(xv.x & 0xffff));
        float s1 = 0.9f*a[1] + 0.1f*bf2f((ushort)(xv.x >> 16));
        float s2 = 0.9f*a[2] + 0.1f*bf2f((ushort)(xv.y & 0xffff));
        float s3 = 0.9f*a[3] + 0.1f*bf2f((ushort)(xv.y >> 16));
        float s4 = 0.9f*a[4] + 0.1f*bf2f((ushort)(xv.z & 0xffff));
        float s5 = 0.9f*a[5] + 0.1f*bf2f((ushort)(xv.z >> 16));
        float s6 = 0.9f*a[6] + 0.1f*bf2f((ushort)(xv.w & 0xffff));
        float s7 = 0.9f*a[7] + 0.1f*bf2f((ushort)(xv.w >> 16));
        pk.x = (uint)f2bf(s0) | ((uint)f2bf(s1) << 16);
        pk.y = (uint)f2bf(s2) | ((uint)f2bf(s3) << 16);
        pk.z = (uint)f2bf(s4) | ((uint)f2bf(s5) << 16);
        pk.w = (uint)f2bf(s6) | ((uint)f2bf(s7) << 16);
      }
      *(uint4*)(&Sm[row*128 + ((lr ^ (row & 15))*8)]) = pk;
    }
  }

  // ---- B fragments (W'^T slice for this wave's 32 cols) ----
  short8 bfr[2][4];
  #pragma unroll
  for (int c = 0; c < 2; ++c)
    #pragma unroll
    for (int ks = 0; ks < 4; ++ks)
      bfr[c][ks] = *(const short8*)(BT + (size_t)(w*32 + c*16 + lr)*H + ks*32 + q*8);

  __syncthreads();

  // ---- GEMM phase: 64 rows x 32 cols per wave ----
  f32x4 acc[4][2];
  #pragma unroll
  for (int rt = 0; rt < 4; ++rt){
    acc[rt][0] = (f32x4){0.f,0.f,0.f,0.f};
    acc[rt][1] = (f32x4){0.f,0.f,0.f,0.f};
  }
  #pragma unroll
  for (int rt = 0; rt < 4; ++rt){
    int row = rt*16 + lr;
    #pragma unroll
    for (int ks = 0; ks < 4; ++ks){
      short8 af = *(const short8*)(&Sm[row*128 + (((ks*4 + q) ^ (row & 15))*8)]);
      acc[rt][0] = __builtin_amdgcn_mfma_f32_16x16x32_bf16(af, bfr[0][ks], acc[rt][0], 0,0,0);
      acc[rt][1] = __builtin_amdgcn_mfma_f32_16x16x32_bf16(af, bfr[1][ks], acc[rt][1], 0,0,0);
    }
  }

  // ---- epilogue: write z, accumulate BN stats ----
  #pragma unroll
  for (int rt = 0; rt < 4; ++rt){
    #pragma unroll
    for (int c = 0; c < 2; ++c){
      #pragma unroll
      for (int j = 0; j < 4; ++j){
        int row = base + rt*16 + q*4 + j;
        float v = acc[rt][c][j];
        if (OUTF32){
          if (row < n)
            ((float*)zout)[(size_t)row*H + w*32 + c*16 + lr] = v;
        } else {
          float other = __shfl(v, l ^ 1);
          if (!(lr & 1) && row < n){
            uint pk = (uint)f2bf(v) | ((uint)f2bf(other) << 16);
            ((uint*)zout)[(size_t)row*64 + w*16 + c*8 + (lr >> 1)] = pk;
          }
        }
      }
    }
  }
  if (STATS){
    #pragma unroll
    for (int c = 0; c < 2; ++c){
      float sv = 0.f, sq = 0.f;
      #pragma unroll
      for (int rt = 0; rt < 4; ++rt)
        #pragma unroll
        for (int j = 0; j < 4; ++j){
          float v = acc[rt][c][j];   // rows >= n have s=0 -> acc=0, contribute 0
          sv += v; sq += v*v;
        }
      sv += __shfl(sv, l ^ 16); sv += __shfl(sv, l ^ 32);
      sq += __shfl(sq, l ^ 16); sq += __shfl(sq, l ^ 32);
      if (q == 0){
        float* st = stats + (size_t)(blockIdx.x & (RSTATS-1))*256;
        atomicAdd(&st[w*32 + c*16 + lr], sv);
        atomicAdd(&st[128 + w*32 + c*16 + lr], sq);
      }
    }
  }
}

// ---------------- BN finalize: stats replicas -> scale/shift ----------------

__global__ void k_bnfinal(const float* __restrict__ stats, const float* __restrict__ gamma,
                          const float* __restrict__ beta, float* __restrict__ scsh,
                          float inv_n){
  int f = threadIdx.x;   // 128
  float s = 0.f, s2 = 0.f;
  for (int r = 0; r < RSTATS; ++r){
    s  += stats[r*256 + f];
    s2 += stats[r*256 + 128 + f];
  }
  float mu  = s * inv_n;
  float var = s2 * inv_n - mu*mu;
  float sc  = rsqrtf(var + EPS_BN) * gamma[f];
  scsh[f]       = sc;
  scsh[128 + f] = beta[f] - mu*sc;
}

// ---------------- MFMA GEMM for input layer: xw = x(f32) @ lin0T^T ----------

__global__ __launch_bounds__(256) void k_gemm0(
    const float* __restrict__ Af, const ushort* __restrict__ BT,
    ushort* __restrict__ Cb, int n){
  const int K = 256;
  __shared__ ushort As[64*32];
  __shared__ ushort Bs[128*32];
  int t = threadIdx.x;
  int br = blockIdx.x * 64;
  int w = t >> 6, l = t & 63;
  int lr = l & 15, lk = l >> 4;
  int swz = (lr >> 1) & 3;

  f32x4 acc[8];
  #pragma unroll
  for (int i = 0; i < 8; ++i) acc[i] = (f32x4){0.f,0.f,0.f,0.f};

  int sar = t >> 2;
  int sab = t & 3;
  int sa_off = sar*32 + ((sab ^ ((sar>>1)&3))*8);

  for (int k0 = 0; k0 < K; k0 += 32){
    int grow = br + sar;
    float4 v0 = make_float4(0.f,0.f,0.f,0.f), v1 = v0;
    if (grow < n){
      v0 = *(const float4*)(Af + (size_t)grow*K + k0 + sab*8);
      v1 = *(const float4*)(Af + (size_t)grow*K + k0 + sab*8 + 4);
    }
    ushort tmp[8] = {f2bf(v0.x),f2bf(v0.y),f2bf(v0.z),f2bf(v0.w),
                     f2bf(v1.x),f2bf(v1.y),f2bf(v1.z),f2bf(v1.w)};
    *(uint4*)(&As[sa_off]) = *(const uint4*)tmp;
    #pragma unroll
    for (int i = 0; i < 2; ++i){
      int qq = t + i*256;
      int nrow = qq >> 2, bb = qq & 3;
      uint4 v = *(const uint4*)(BT + (size_t)nrow*K + k0 + bb*8);
      *(uint4*)(&Bs[nrow*32 + ((bb ^ ((nrow>>1)&3))*8)]) = v;
    }
    __syncthreads();
    short8 af = *(const short8*)(&As[(w*16+lr)*32 + ((lk ^ swz)*8)]);
    #pragma unroll
    for (int tn = 0; tn < 8; ++tn){
      short8 bfv = *(const short8*)(&Bs[(tn*16+lr)*32 + ((lk ^ swz)*8)]);
      acc[tn] = __builtin_amdgcn_mfma_f32_16x16x32_bf16(af, bfv, acc[tn], 0, 0, 0);
    }
    __syncthreads();
  }
  int orow = br + w*16 + lk*4;
  #pragma unroll
  for (int tn = 0; tn < 8; ++tn){
    #pragma unroll
    for (int j = 0; j < 4; ++j){
      float mine  = acc[tn][j];
      float other = __shfl(mine, l ^ 1);
      if (!(l & 1) && (orow + j) < n){
        uint pk = (uint)f2bf(mine) | ((uint)f2bf(other) << 16);
        ((uint*)Cb)[(size_t)(orow+j)*64 + tn*8 + (lr >> 1)] = pk;
      }
    }
  }
}

// ---------------- launch ----------------

extern "C" void kernel_launch(void* const* d_in, const int* in_sizes, int n_in,
                              void* d_out, int out_size, void* d_ws, size_t ws_size,
                              hipStream_t stream){
  const float* x        = (const float*)d_in[0];
  const int*   ei       = (const int*)  d_in[1];
  const float* lin0_w   = (const float*)d_in[2];
  const float* lin0_b   = (const float*)d_in[3];
  const float* conv_w   = (const float*)d_in[4];
  const float* bn_gamma = (const float*)d_in[5];
  const float* bn_beta  = (const float*)d_in[6];
  float* out = (float*)d_out;

  int N = in_sizes[0] / 256;
  int E = in_sizes[1] / 2;
  const int* row = ei;
  const int* col = ei + E;

  char* ws = (char*)d_ws;
  size_t p = 0;
  auto alloc = [&](size_t bytes)->char*{
    char* r = ws + p; p = (p + bytes + 255) & ~(size_t)255; return r;
  };
  int*    cnt    = (int*)   alloc((size_t)N*4);
  int*    off    = (int*)   alloc((size_t)(N+1)*4);
  int*    cursor = (int*)   alloc((size_t)N*4);
  float*  dinv   = (float*) alloc((size_t)N*4);
  int*    bsum   = (int*)   alloc(512*4);
  uint2*  edge   = (uint2*) alloc((size_t)E*8);
  ushort* zb     = (ushort*)alloc((size_t)N*H*2);
  ushort* sb     = (ushort*)alloc((size_t)N*H*2);   // xw, then ping-pong z
  ushort* x0b    = (ushort*)alloc((size_t)N*H*2);
  ushort* lin0T  = (ushort*)alloc(128*256*2);
  ushort* WpT    = (ushort*)alloc(4*128*128*2);
  float*  stats  = (float*) alloc(RSTATS*256*4);
  float*  scsh   = (float*) alloc(2*128*4);

  float betas[4];
  for (int i = 0; i < 4; ++i) betas[i] = logf(0.5f/(float)(i+1) + 1.0f);
  float inv_n = 1.0f/(float)N;

  // ---- CSR build ----
  hipMemsetAsync(cnt, 0, (size_t)N*4, stream);
  k_count<<<(E+255)/256, 256, 0, stream>>>(col, E, cnt);
  k_dinv <<<(N+255)/256, 256, 0, stream>>>(cnt, dinv, N);
  int nb = (N + 1023)/1024;
  k_scan1<<<nb, 1024, 0, stream>>>(cnt, off, bsum, N);
  k_scan2<<<1, 64, 0, stream>>>(bsum, nb);
  k_scan3<<<(N+255)/256, 256, 0, stream>>>(off, cursor, bsum, N, E);
  k_fill <<<(E+255)/256, 256, 0, stream>>>(row, col, E, dinv, cursor, edge);

  k_prepw<<<(128*256 + 4*128*128 + 255)/256, 256, 0, stream>>>(
      lin0_w, conv_w, lin0T, WpT, betas[0], betas[1], betas[2], betas[3]);

  int lay_blocks  = (N + 63)/64;
  int prop_blocks = ((N*64) + 255)/256;

  // ---- input layer ----
  k_gemm0<<<lay_blocks, 256, 0, stream>>>(x, lin0T, sb, N);
  k_prop0<<<prop_blocks, 256, 0, stream>>>(sb, off, edge, dinv, lin0_b, zb, x0b, N);

  // ---- layer 0: zin=zb -> zout=sb, stats ----
  hipMemsetAsync(stats, 0, RSTATS*256*4, stream);
  k_layer<false,true,false><<<lay_blocks, 256, 0, stream>>>(
      zb, x0b, off, edge, dinv, WpT + 0*128*128, nullptr, sb, stats, N);
  k_bnfinal<<<1, 128, 0, stream>>>(stats, bn_gamma + 0*H, bn_beta + 0*H, scsh, inv_n);

  // ---- layer 1: zin=sb -> zout=zb, stats ----
  hipMemsetAsync(stats, 0, RSTATS*256*4, stream);
  k_layer<true,true,false><<<lay_blocks, 256, 0, stream>>>(
      sb, x0b, off, edge, dinv, WpT + 1*128*128, scsh, zb, stats, N);
  k_bnfinal<<<1, 128, 0, stream>>>(stats, bn_gamma + 1*H, bn_beta + 1*H, scsh, inv_n);

  // ---- layer 2: zin=zb -> zout=sb, stats ----
  hipMemsetAsync(stats, 0, RSTATS*256*4, stream);
  k_layer<true,true,false><<<lay_blocks, 256, 0, stream>>>(
      zb, x0b, off, edge, dinv, WpT + 2*128*128, scsh, sb, stats, N);
  k_bnfinal<<<1, 128, 0, stream>>>(stats, bn_gamma + 2*H, bn_beta + 2*H, scsh, inv_n);

  // ---- layer 3: zin=sb -> out (f32), no stats ----
  k_layer<true,false,true><<<lay_blocks, 256, 0, stream>>>(
      sb, x0b, off, edge, dinv, WpT + 3*128*128, scsh, out, nullptr, N);
}

// Round 4
// 677.881 us; speedup vs baseline: 2.1016x; 1.3245x over previous
//
#include <hip/hip_runtime.h>
#include <hip/hip_bf16.h>
#include <math.h>

#define H 128
#define EPS_BN 1e-5f
#define RSTATS 16

typedef __attribute__((ext_vector_type(8))) short short8;
typedef __attribute__((ext_vector_type(4))) float f32x4;

__device__ __forceinline__ float bf2f(ushort u){
  union { float f; uint v; } x; x.v = ((uint)u) << 16; return x.f;
}
__device__ __forceinline__ ushort f2bf(float f){
  union { float f; uint v; } x; x.f = f;
  uint v = x.v;
  uint r = v + 0x7fff + ((v >> 16) & 1);   // RNE
  return (ushort)(r >> 16);
}

__device__ __forceinline__ void acc8(float* a, uint4 v, float wt){
  a[0] += wt*bf2f((ushort)(v.x & 0xffff)); a[1] += wt*bf2f((ushort)(v.x >> 16));
  a[2] += wt*bf2f((ushort)(v.y & 0xffff)); a[3] += wt*bf2f((ushort)(v.y >> 16));
  a[4] += wt*bf2f((ushort)(v.z & 0xffff)); a[5] += wt*bf2f((ushort)(v.z >> 16));
  a[6] += wt*bf2f((ushort)(v.w & 0xffff)); a[7] += wt*bf2f((ushort)(v.w >> 16));
}
__device__ __forceinline__ void acc8bn(float* a, uint4 v, float wt,
                                       const float* sc, const float* sh){
  float z[8] = { bf2f((ushort)(v.x & 0xffff)), bf2f((ushort)(v.x >> 16)),
                 bf2f((ushort)(v.y & 0xffff)), bf2f((ushort)(v.y >> 16)),
                 bf2f((ushort)(v.z & 0xffff)), bf2f((ushort)(v.z >> 16)),
                 bf2f((ushort)(v.w & 0xffff)), bf2f((ushort)(v.w >> 16)) };
  #pragma unroll
  for (int j = 0; j < 8; ++j){
    float y = fmaf(z[j], sc[j], sh[j]);
    y = fmaxf(y, 0.f);
    a[j] += wt*y;
  }
}

// ---------------- CSR build ----------------

__global__ void k_count(const int* __restrict__ col, int E, int* __restrict__ cnt){
  int i = blockIdx.x*blockDim.x + threadIdx.x;
  if (i < E) atomicAdd(&cnt[col[i]], 1);
}

__global__ void k_dinv(const int* __restrict__ cnt, float* __restrict__ dinv, int n){
  int i = blockIdx.x*blockDim.x + threadIdx.x;
  if (i < n) dinv[i] = rsqrtf((float)cnt[i] + 1.0f);   // +1 self-loop
}

__global__ void k_scan1(const int* __restrict__ cnt, int* __restrict__ off,
                        int* __restrict__ bsum, int n){
  __shared__ int s[1024];
  int t = threadIdx.x;
  int i = blockIdx.x*1024 + t;
  int v = (i < n) ? cnt[i] : 0;
  s[t] = v; __syncthreads();
  for (int d = 1; d < 1024; d <<= 1){
    int x = (t >= d) ? s[t-d] : 0;
    __syncthreads();
    s[t] += x;
    __syncthreads();
  }
  if (i < n) off[i] = s[t] - v;
  if (t == 1023) bsum[blockIdx.x] = s[1023];
}

__global__ void k_scan2(int* bsum, int nb){
  int l = threadIdx.x;           // 64 threads, 1 block
  int carry = 0;
  for (int b0 = 0; b0 < nb; b0 += 64){
    int i = b0 + l;
    int orig = (i < nb) ? bsum[i] : 0;
    int v = orig;
    #pragma unroll
    for (int d = 1; d < 64; d <<= 1){
      int x = __shfl_up(v, d);
      if (l >= d) v += x;
    }
    if (i < nb) bsum[i] = carry + v - orig;   // exclusive
    carry += __shfl(v, 63);
  }
}

__global__ void k_scan3(int* __restrict__ off, int* __restrict__ cursor,
                        const int* __restrict__ bsum, int n, int Etot){
  int i = blockIdx.x*blockDim.x + threadIdx.x;
  if (i < n){ int o = off[i] + bsum[i >> 10]; off[i] = o; cursor[i] = o; }
  if (i == 0) off[n] = Etot;
}

__global__ void k_fill(const int* __restrict__ row, const int* __restrict__ col, int E,
                       const float* __restrict__ dinv, int* __restrict__ cursor,
                       uint2* __restrict__ edge){
  int i = blockIdx.x*blockDim.x + threadIdx.x;
  if (i < E){
    int c = col[i], r = row[i];
    int p = atomicAdd(&cursor[c], 1);
    edge[p] = make_uint2((uint)r, __float_as_uint(dinv[r]*dinv[c]));
  }
}

// ---------------- weight prep: bf16, transposed, beta-folded ----------------

__global__ void k_prepw(const float* __restrict__ lin0_w, const float* __restrict__ conv_w,
                        ushort* __restrict__ lin0T, ushort* __restrict__ WpT,
                        float b0, float b1, float b2, float b3){
  int i = blockIdx.x*blockDim.x + threadIdx.x;
  if (i < 128*256){
    int nn = i >> 8, k = i & 255;
    lin0T[i] = f2bf(lin0_w[k*128 + nn]);
  } else if (i < 128*256 + 4*128*128){
    int j = i - 128*256;
    int ll = j >> 14, rc = j & 16383;
    int nn = rc >> 7, k = rc & 127;
    float beta = (ll==0)?b0:(ll==1)?b1:(ll==2)?b2:b3;
    float v = beta * conv_w[ll*16384 + k*128 + nn];
    if (k == nn) v += 1.0f - beta;
    WpT[j] = f2bf(v);
  }
}

// ---------------- input-layer prop: z = agg(xw)+b ; x0 = z ----------------
// quarter-wave per edge, unroll x2 (8 gathers in flight per wave)

__global__ __launch_bounds__(256) void k_prop0(
    const ushort* __restrict__ h, const int* __restrict__ off,
    const uint2* __restrict__ edge, const float* __restrict__ dinv,
    const float* __restrict__ bias,
    ushort* __restrict__ z, ushort* __restrict__ x0, int n){
  int g = blockIdx.x*blockDim.x + threadIdx.x;
  int node = g >> 6;
  if (node >= n) return;
  int l = g & 63, lr = l & 15, q = l >> 4;
  int e0 = off[node], e1 = off[node+1];
  float a[8];
  #pragma unroll
  for (int j = 0; j < 8; ++j) a[j] = 0.f;
  int e = e0 + q;
  for (; e + 4 < e1; e += 8){
    uint2 edA = edge[e];
    uint2 edB = edge[e+4];
    uint4 vA = *(const uint4*)(h + (size_t)edA.x*H + lr*8);
    uint4 vB = *(const uint4*)(h + (size_t)edB.x*H + lr*8);
    acc8(a, vA, __uint_as_float(edA.y));
    acc8(a, vB, __uint_as_float(edB.y));
  }
  if (e < e1){
    uint2 ed = edge[e];
    uint4 v = *(const uint4*)(h + (size_t)ed.x*H + lr*8);
    acc8(a, v, __uint_as_float(ed.y));
  }
  if (q == 0){
    float wc = dinv[node]; wc *= wc;
    uint4 v = *(const uint4*)(h + (size_t)node*H + lr*8);
    acc8(a, v, wc);
  }
  #pragma unroll
  for (int j = 0; j < 8; ++j){
    a[j] += __shfl(a[j], l ^ 16);
    a[j] += __shfl(a[j], l ^ 32);
  }
  if (q == 0){
    float4 b0 = *(const float4*)(bias + lr*8);
    float4 b1 = *(const float4*)(bias + lr*8 + 4);
    uint4 pk;
    pk.x = (uint)f2bf(a[0]+b0.x) | ((uint)f2bf(a[1]+b0.y) << 16);
    pk.y = (uint)f2bf(a[2]+b0.z) | ((uint)f2bf(a[3]+b0.w) << 16);
    pk.z = (uint)f2bf(a[4]+b1.x) | ((uint)f2bf(a[5]+b1.y) << 16);
    pk.w = (uint)f2bf(a[6]+b1.z) | ((uint)f2bf(a[7]+b1.w) << 16);
    size_t o = (size_t)node*H + lr*8;
    *(uint4*)(z  + o) = pk;
    *(uint4*)(x0 + o) = pk;
  }
}

// ---------------- fused layer: prop -> LDS s-tile -> MFMA GEMM -> z (+stats) --
// block = 256 thr (4 waves) = 32 nodes. Wave w: nodes [w*8, w*8+8).
// GEMM: 32 rows x 128 cols; wave w owns cols [w*32, w*32+32), B in registers.

template<bool BNIN, bool STATS, bool OUTF32>
__global__ __launch_bounds__(256) void k_layer(
    const ushort* __restrict__ zin, const ushort* __restrict__ x0,
    const int* __restrict__ off, const uint2* __restrict__ edge,
    const float* __restrict__ dinv, const ushort* __restrict__ BT,
    const float* __restrict__ scsh,
    void* __restrict__ zout, float* __restrict__ stats, int n)
{
  __shared__ ushort Sm[32*128];   // swizzled s tile: row*128 + ((blk16^(row&15))*8)
  int t = threadIdx.x;
  int w = t >> 6, l = t & 63;
  int lr = l & 15, q = l >> 4;
  int base = blockIdx.x * 32;

  float sc[8], sh[8];
  if (BNIN){
    #pragma unroll
    for (int j = 0; j < 8; ++j){
      sc[j] = scsh[lr*8 + j];
      sh[j] = scsh[128 + lr*8 + j];
    }
  }

  // ---- prop phase: 8 nodes per wave ----
  for (int nd = 0; nd < 8; ++nd){
    int node = base + w*8 + nd;
    float a[8];
    #pragma unroll
    for (int j = 0; j < 8; ++j) a[j] = 0.f;
    if (node < n){
      int e0 = off[node], e1 = off[node+1];
      int e = e0 + q;
      for (; e + 4 < e1; e += 8){
        uint2 edA = edge[e];
        uint2 edB = edge[e+4];
        uint4 vA = *(const uint4*)(zin + (size_t)edA.x*H + lr*8);
        uint4 vB = *(const uint4*)(zin + (size_t)edB.x*H + lr*8);
        float wA = __uint_as_float(edA.y);
        float wB = __uint_as_float(edB.y);
        if (BNIN){ acc8bn(a, vA, wA, sc, sh); acc8bn(a, vB, wB, sc, sh); }
        else     { acc8(a, vA, wA);           acc8(a, vB, wB); }
      }
      if (e < e1){
        uint2 ed = edge[e];
        uint4 v = *(const uint4*)(zin + (size_t)ed.x*H + lr*8);
        float wt = __uint_as_float(ed.y);
        if (BNIN) acc8bn(a, v, wt, sc, sh); else acc8(a, v, wt);
      }
      if (q == 0){
        float wc = dinv[node]; wc *= wc;
        uint4 v = *(const uint4*)(zin + (size_t)node*H + lr*8);
        if (BNIN) acc8bn(a, v, wc, sc, sh); else acc8(a, v, wc);
      }
    }
    #pragma unroll
    for (int j = 0; j < 8; ++j){
      a[j] += __shfl(a[j], l ^ 16);
      a[j] += __shfl(a[j], l ^ 32);
    }
    if (q == 0){
      int row = w*8 + nd;
      uint4 pk = make_uint4(0u,0u,0u,0u);
      if (node < n){
        uint4 xv = *(const uint4*)(x0 + (size_t)node*H + lr*8);
        float s0 = 0.9f*a[0] + 0.1f*bf2f((ushort)(xv.x & 0xffff));
        float s1 = 0.9f*a[1] + 0.1f*bf2f((ushort)(xv.x >> 16));
        float s2 = 0.9f*a[2] + 0.1f*bf2f((ushort)(xv.y & 0xffff));
        float s3 = 0.9f*a[3] + 0.1f*bf2f((ushort)(xv.y >> 16));
        float s4 = 0.9f*a[4] + 0.1f*bf2f((ushort)(xv.z & 0xffff));
        float s5 = 0.9f*a[5] + 0.1f*bf2f((ushort)(xv.z >> 16));
        float s6 = 0.9f*a[6] + 0.1f*bf2f((ushort)(xv.w & 0xffff));
        float s7 = 0.9f*a[7] + 0.1f*bf2f((ushort)(xv.w >> 16));
        pk.x = (uint)f2bf(s0) | ((uint)f2bf(s1) << 16);
        pk.y = (uint)f2bf(s2) | ((uint)f2bf(s3) << 16);
        pk.z = (uint)f2bf(s4) | ((uint)f2bf(s5) << 16);
        pk.w = (uint)f2bf(s6) | ((uint)f2bf(s7) << 16);
      }
      *(uint4*)(&Sm[row*128 + ((lr ^ (row & 15))*8)]) = pk;
    }
  }

  // ---- B fragments (W'^T slice for this wave's 32 cols) ----
  short8 bfr[2][4];
  #pragma unroll
  for (int c = 0; c < 2; ++c)
    #pragma unroll
    for (int ks = 0; ks < 4; ++ks)
      bfr[c][ks] = *(const short8*)(BT + (size_t)(w*32 + c*16 + lr)*H + ks*32 + q*8);

  __syncthreads();

  // ---- GEMM phase: 32 rows x 32 cols per wave ----
  f32x4 acc[2][2];
  #pragma unroll
  for (int rt = 0; rt < 2; ++rt){
    acc[rt][0] = (f32x4){0.f,0.f,0.f,0.f};
    acc[rt][1] = (f32x4){0.f,0.f,0.f,0.f};
  }
  #pragma unroll
  for (int rt = 0; rt < 2; ++rt){
    int row = rt*16 + lr;
    #pragma unroll
    for (int ks = 0; ks < 4; ++ks){
      short8 af = *(const short8*)(&Sm[row*128 + (((ks*4 + q) ^ (row & 15))*8)]);
      acc[rt][0] = __builtin_amdgcn_mfma_f32_16x16x32_bf16(af, bfr[0][ks], acc[rt][0], 0,0,0);
      acc[rt][1] = __builtin_amdgcn_mfma_f32_16x16x32_bf16(af, bfr[1][ks], acc[rt][1], 0,0,0);
    }
  }

  // ---- epilogue: write z, accumulate BN stats ----
  #pragma unroll
  for (int rt = 0; rt < 2; ++rt){
    #pragma unroll
    for (int c = 0; c < 2; ++c){
      #pragma unroll
      for (int j = 0; j < 4; ++j){
        int row = base + rt*16 + q*4 + j;
        float v = acc[rt][c][j];
        if (OUTF32){
          if (row < n)
            ((float*)zout)[(size_t)row*H + w*32 + c*16 + lr] = v;
        } else {
          float other = __shfl(v, l ^ 1);
          if (!(lr & 1) && row < n){
            uint pk = (uint)f2bf(v) | ((uint)f2bf(other) << 16);
            ((uint*)zout)[(size_t)row*64 + w*16 + c*8 + (lr >> 1)] = pk;
          }
        }
      }
    }
  }
  if (STATS){
    #pragma unroll
    for (int c = 0; c < 2; ++c){
      float sv = 0.f, sq = 0.f;
      #pragma unroll
      for (int rt = 0; rt < 2; ++rt)
        #pragma unroll
        for (int j = 0; j < 4; ++j){
          float v = acc[rt][c][j];   // rows >= n have s=0 -> acc=0
          sv += v; sq += v*v;
        }
      sv += __shfl(sv, l ^ 16); sv += __shfl(sv, l ^ 32);
      sq += __shfl(sq, l ^ 16); sq += __shfl(sq, l ^ 32);
      if (q == 0){
        float* st = stats + (size_t)(blockIdx.x & (RSTATS-1))*256;
        atomicAdd(&st[w*32 + c*16 + lr], sv);
        atomicAdd(&st[128 + w*32 + c*16 + lr], sq);
      }
    }
  }
}

// ---------------- BN finalize: stats replicas -> scale/shift ----------------

__global__ void k_bnfinal(const float* __restrict__ stats, const float* __restrict__ gamma,
                          const float* __restrict__ beta, float* __restrict__ scsh,
                          float inv_n){
  int f = threadIdx.x;   // 128
  float s = 0.f, s2 = 0.f;
  for (int r = 0; r < RSTATS; ++r){
    s  += stats[r*256 + f];
    s2 += stats[r*256 + 128 + f];
  }
  float mu  = s * inv_n;
  float var = s2 * inv_n - mu*mu;
  float sc  = rsqrtf(var + EPS_BN) * gamma[f];
  scsh[f]       = sc;
  scsh[128 + f] = beta[f] - mu*sc;
}

// ---------------- MFMA GEMM for input layer: xw = x(f32) @ lin0T^T ----------

__global__ __launch_bounds__(256) void k_gemm0(
    const float* __restrict__ Af, const ushort* __restrict__ BT,
    ushort* __restrict__ Cb, int n){
  const int K = 256;
  __shared__ ushort As[64*32];
  __shared__ ushort Bs[128*32];
  int t = threadIdx.x;
  int br = blockIdx.x * 64;
  int w = t >> 6, l = t & 63;
  int lr = l & 15, lk = l >> 4;
  int swz = (lr >> 1) & 3;

  f32x4 acc[8];
  #pragma unroll
  for (int i = 0; i < 8; ++i) acc[i] = (f32x4){0.f,0.f,0.f,0.f};

  int sar = t >> 2;
  int sab = t & 3;
  int sa_off = sar*32 + ((sab ^ ((sar>>1)&3))*8);

  for (int k0 = 0; k0 < K; k0 += 32){
    int grow = br + sar;
    float4 v0 = make_float4(0.f,0.f,0.f,0.f), v1 = v0;
    if (grow < n){
      v0 = *(const float4*)(Af + (size_t)grow*K + k0 + sab*8);
      v1 = *(const float4*)(Af + (size_t)grow*K + k0 + sab*8 + 4);
    }
    ushort tmp[8] = {f2bf(v0.x),f2bf(v0.y),f2bf(v0.z),f2bf(v0.w),
                     f2bf(v1.x),f2bf(v1.y),f2bf(v1.z),f2bf(v1.w)};
    *(uint4*)(&As[sa_off]) = *(const uint4*)tmp;
    #pragma unroll
    for (int i = 0; i < 2; ++i){
      int qq = t + i*256;
      int nrow = qq >> 2, bb = qq & 3;
      uint4 v = *(const uint4*)(BT + (size_t)nrow*K + k0 + bb*8);
      *(uint4*)(&Bs[nrow*32 + ((bb ^ ((nrow>>1)&3))*8)]) = v;
    }
    __syncthreads();
    short8 af = *(const short8*)(&As[(w*16+lr)*32 + ((lk ^ swz)*8)]);
    #pragma unroll
    for (int tn = 0; tn < 8; ++tn){
      short8 bfv = *(const short8*)(&Bs[(tn*16+lr)*32 + ((lk ^ swz)*8)]);
      acc[tn] = __builtin_amdgcn_mfma_f32_16x16x32_bf16(af, bfv, acc[tn], 0, 0, 0);
    }
    __syncthreads();
  }
  int orow = br + w*16 + lk*4;
  #pragma unroll
  for (int tn = 0; tn < 8; ++tn){
    #pragma unroll
    for (int j = 0; j < 4; ++j){
      float mine  = acc[tn][j];
      float other = __shfl(mine, l ^ 1);
      if (!(l & 1) && (orow + j) < n){
        uint pk = (uint)f2bf(mine) | ((uint)f2bf(other) << 16);
        ((uint*)Cb)[(size_t)(orow+j)*64 + tn*8 + (lr >> 1)] = pk;
      }
    }
  }
}

// ---------------- launch ----------------

extern "C" void kernel_launch(void* const* d_in, const int* in_sizes, int n_in,
                              void* d_out, int out_size, void* d_ws, size_t ws_size,
                              hipStream_t stream){
  const float* x        = (const float*)d_in[0];
  const int*   ei       = (const int*)  d_in[1];
  const float* lin0_w   = (const float*)d_in[2];
  const float* lin0_b   = (const float*)d_in[3];
  const float* conv_w   = (const float*)d_in[4];
  const float* bn_gamma = (const float*)d_in[5];
  const float* bn_beta  = (const float*)d_in[6];
  float* out = (float*)d_out;

  int N = in_sizes[0] / 256;
  int E = in_sizes[1] / 2;
  const int* row = ei;
  const int* col = ei + E;

  char* ws = (char*)d_ws;
  size_t p = 0;
  auto alloc = [&](size_t bytes)->char*{
    char* r = ws + p; p = (p + bytes + 255) & ~(size_t)255; return r;
  };
  int*    cnt    = (int*)   alloc((size_t)N*4);
  int*    off    = (int*)   alloc((size_t)(N+1)*4);
  int*    cursor = (int*)   alloc((size_t)N*4);
  float*  dinv   = (float*) alloc((size_t)N*4);
  int*    bsum   = (int*)   alloc(512*4);
  uint2*  edge   = (uint2*) alloc((size_t)E*8);
  ushort* zb     = (ushort*)alloc((size_t)N*H*2);
  ushort* sb     = (ushort*)alloc((size_t)N*H*2);   // xw, then ping-pong z
  ushort* x0b    = (ushort*)alloc((size_t)N*H*2);
  ushort* lin0T  = (ushort*)alloc(128*256*2);
  ushort* WpT    = (ushort*)alloc(4*128*128*2);
  float*  stats  = (float*) alloc(RSTATS*256*4);
  float*  scsh   = (float*) alloc(2*128*4);

  float betas[4];
  for (int i = 0; i < 4; ++i) betas[i] = logf(0.5f/(float)(i+1) + 1.0f);
  float inv_n = 1.0f/(float)N;

  // ---- CSR build ----
  hipMemsetAsync(cnt, 0, (size_t)N*4, stream);
  k_count<<<(E+255)/256, 256, 0, stream>>>(col, E, cnt);
  k_dinv <<<(N+255)/256, 256, 0, stream>>>(cnt, dinv, N);
  int nb = (N + 1023)/1024;
  k_scan1<<<nb, 1024, 0, stream>>>(cnt, off, bsum, N);
  k_scan2<<<1, 64, 0, stream>>>(bsum, nb);
  k_scan3<<<(N+255)/256, 256, 0, stream>>>(off, cursor, bsum, N, E);
  k_fill <<<(E+255)/256, 256, 0, stream>>>(row, col, E, dinv, cursor, edge);

  k_prepw<<<(128*256 + 4*128*128 + 255)/256, 256, 0, stream>>>(
      lin0_w, conv_w, lin0T, WpT, betas[0], betas[1], betas[2], betas[3]);

  int gemm_blocks = (N + 63)/64;
  int lay_blocks  = (N + 31)/32;
  int prop_blocks = ((N*64) + 255)/256;

  // ---- input layer ----
  k_gemm0<<<gemm_blocks, 256, 0, stream>>>(x, lin0T, sb, N);
  k_prop0<<<prop_blocks, 256, 0, stream>>>(sb, off, edge, dinv, lin0_b, zb, x0b, N);

  // ---- layer 0: zin=zb -> zout=sb, stats ----
  hipMemsetAsync(stats, 0, RSTATS*256*4, stream);
  k_layer<false,true,false><<<lay_blocks, 256, 0, stream>>>(
      zb, x0b, off, edge, dinv, WpT + 0*128*128, nullptr, sb, stats, N);
  k_bnfinal<<<1, 128, 0, stream>>>(stats, bn_gamma + 0*H, bn_beta + 0*H, scsh, inv_n);

  // ---- layer 1: zin=sb -> zout=zb, stats ----
  hipMemsetAsync(stats, 0, RSTATS*256*4, stream);
  k_layer<true,true,false><<<lay_blocks, 256, 0, stream>>>(
      sb, x0b, off, edge, dinv, WpT + 1*128*128, scsh, zb, stats, N);
  k_bnfinal<<<1, 128, 0, stream>>>(stats, bn_gamma + 1*H, bn_beta + 1*H, scsh, inv_n);

  // ---- layer 2: zin=zb -> zout=sb, stats ----
  hipMemsetAsync(stats, 0, RSTATS*256*4, stream);
  k_layer<true,true,false><<<lay_blocks, 256, 0, stream>>>(
      zb, x0b, off, edge, dinv, WpT + 2*128*128, scsh, sb, stats, N);
  k_bnfinal<<<1, 128, 0, stream>>>(stats, bn_gamma + 2*H, bn_beta + 2*H, scsh, inv_n);

  // ---- layer 3: zin=sb -> out (f32), no stats ----
  k_layer<true,false,true><<<lay_blocks, 256, 0, stream>>>(
      sb, x0b, off, edge, dinv, WpT + 3*128*128, scsh, out, nullptr, N);
}